// Round 1
// baseline (379.107 us; speedup 1.0000x reference)
//
#include <hip/hip_runtime.h>

#define DFEAT 64
#define EPSBN 1e-5f
#define SCB 2048      // elements per scan block (256 threads x 8)
#define CHUNK_LG 15
#define CHUNK (1 << CHUNK_LG)   // 32768 edges per chunk (637 blocks -> 2.5/CU)
#define RNG 8192      // nodes per partition (one packed 32KB LDS histogram)

// ---------------- LDS-privatized PACKED dual histogram + chunk-local rank ----------------
// one 32KB LDS array: low16 = dst count, high16 = src count. int4 edge loads +
// manual prefetch.
__global__ __launch_bounds__(256) void hist2d_kernel(
        const int* __restrict__ src, const int* __restrict__ dst,
        unsigned short* __restrict__ lrank, unsigned short* __restrict__ cnt,
        int* __restrict__ deg_out, int E, int N, int N_pad) {
    __shared__ int h[RNG];
    int tid = threadIdx.x;
    int c = blockIdx.x, p = blockIdx.y;
    int nbeg = p * RNG;
    for (int i = tid; i < RNG; i += 256) h[i] = 0;
    __syncthreads();

    int ebeg = c << CHUNK_LG;
    int eend = min(ebeg + CHUNK, E);
    int nvec = (eend - ebeg) >> 2;              // full int4 groups
    const int4* src4 = (const int4*)(src + ebeg);
    const int4* dst4 = (const int4*)(dst + ebeg);

    int i = tid;
    int4 s4 = make_int4(0, 0, 0, 0), d4 = s4;
    if (i < nvec) { s4 = src4[i]; d4 = dst4[i]; }
    while (i < nvec) {
        int inext = i + 256;
        int4 sn = make_int4(0, 0, 0, 0), dn = sn;
        if (inext < nvec) { sn = src4[inext]; dn = dst4[inext]; }   // prefetch
        int e = ebeg + (i << 2);
        {
            unsigned int so, dof;
            so = (unsigned int)(s4.x - nbeg); if (so < RNG) atomicAdd(&h[so], 0x10000);
            so = (unsigned int)(s4.y - nbeg); if (so < RNG) atomicAdd(&h[so], 0x10000);
            so = (unsigned int)(s4.z - nbeg); if (so < RNG) atomicAdd(&h[so], 0x10000);
            so = (unsigned int)(s4.w - nbeg); if (so < RNG) atomicAdd(&h[so], 0x10000);
            dof = (unsigned int)(d4.x - nbeg);
            if (dof < RNG) lrank[e + 0] = (unsigned short)(atomicAdd(&h[dof], 1) & 0xffff);
            dof = (unsigned int)(d4.y - nbeg);
            if (dof < RNG) lrank[e + 1] = (unsigned short)(atomicAdd(&h[dof], 1) & 0xffff);
            dof = (unsigned int)(d4.z - nbeg);
            if (dof < RNG) lrank[e + 2] = (unsigned short)(atomicAdd(&h[dof], 1) & 0xffff);
            dof = (unsigned int)(d4.w - nbeg);
            if (dof < RNG) lrank[e + 3] = (unsigned short)(atomicAdd(&h[dof], 1) & 0xffff);
        }
        s4 = sn; d4 = dn; i = inext;
    }
    for (int e = ebeg + (nvec << 2) + tid; e < eend; e += 256) {
        unsigned int so = (unsigned int)(src[e] - nbeg);
        unsigned int dof = (unsigned int)(dst[e] - nbeg);
        if (so < RNG) atomicAdd(&h[so], 0x10000);
        if (dof < RNG) lrank[e] = (unsigned short)(atomicAdd(&h[dof], 1) & 0xffff);
    }
    __syncthreads();

    for (int i2 = tid; i2 < RNG; i2 += 256) {
        int n = nbeg + i2;
        if (n < N) {
            unsigned int v = (unsigned int)h[i2];
            unsigned int vo = v >> 16;
            if (vo) atomicAdd(&deg_out[n], (int)vo);   // contiguous lanes -> batched
            cnt[(size_t)c * N_pad + n] = (unsigned short)(v & 0xffffu);
        }
    }
}

// ---------------- column scan: per-node exclusive prefix over chunks ----------------
__global__ void colscan_kernel(unsigned short* __restrict__ cnt,
                               int* __restrict__ deg_in, int N, int N_pad, int C) {
    int n = blockIdx.x * blockDim.x + threadIdx.x;
    if (n >= N) return;
    int run = 0;
    for (int c = 0; c < C; ++c) {
        size_t idx = (size_t)c * N_pad + n;
        int v = cnt[idx];
        cnt[idx] = (unsigned short)run;
        run += v;
    }
    deg_in[n] = run;
}

// ---------------- scan pass 1: per-block sums of deg_in ----------------
__global__ void scan1_kernel(const int* __restrict__ deg, int* __restrict__ bsum, int N) {
    __shared__ int red[256];
    int t = threadIdx.x;
    int base = blockIdx.x * SCB + t * 8;
    int s = 0;
    #pragma unroll
    for (int j = 0; j < 8; ++j) { int idx = base + j; if (idx < N) s += deg[idx]; }
    red[t] = s;
    __syncthreads();
    for (int d = 128; d > 0; d >>= 1) { if (t < d) red[t] += red[t + d]; __syncthreads(); }
    if (t == 0) bsum[blockIdx.x] = red[0];
}

// ---------------- scan pass 2: one-wave shuffle exclusive scan (NB <= 64) ----------------
__global__ void scan2_kernel(int* __restrict__ bsum, int* __restrict__ row_start, int NB, int N) {
    int lane = threadIdx.x & 63;
    int v = (lane < NB) ? bsum[lane] : 0;
    int incl = v;
    #pragma unroll
    for (int off = 1; off < 64; off <<= 1) {
        int t = __shfl_up(incl, off);
        if (lane >= off) incl += t;
    }
    if (lane < NB) bsum[lane] = incl - v;
    if (lane == 63) row_start[N] = incl;   // total == E
}

// ---------------- scan pass 3: full exclusive scan -> row_start ----------------
__global__ void scan3_kernel(const int* __restrict__ deg, const int* __restrict__ bsum,
                             int* __restrict__ row_start, int N) {
    __shared__ int sc[256];
    int t = threadIdx.x;
    int base = blockIdx.x * SCB + t * 8;
    int v[8], ex[8];
    int s = 0;
    #pragma unroll
    for (int j = 0; j < 8; ++j) {
        int idx = base + j;
        v[j] = (idx < N) ? deg[idx] : 0;
        ex[j] = s;
        s += v[j];
    }
    sc[t] = s;
    __syncthreads();
    for (int d = 1; d < 256; d <<= 1) {
        int vv = (t >= d) ? sc[t - d] : 0;
        __syncthreads();
        sc[t] += vv;
        __syncthreads();
    }
    int toff = sc[t] - s + bsum[blockIdx.x];
    #pragma unroll
    for (int j = 0; j < 8; ++j) {
        int idx = base + j;
        if (idx < N) row_start[idx] = toff + ex[j];
    }
}

// ---------------- place edges: slot = row_start[d] + pref[c][d] + lrank[e] ----------------
__global__ void fill_kernel(const int* __restrict__ src, const int* __restrict__ dst,
                            const unsigned short* __restrict__ lrank,
                            const unsigned short* __restrict__ cnt,
                            const int* __restrict__ deg_out, const int* __restrict__ row_start,
                            int2* __restrict__ epack, int E, int N_pad) {
    int e = blockIdx.x * blockDim.x + threadIdx.x;
    if (e < E) {
        int d = dst[e], s = src[e];
        int c = e >> CHUNK_LG;
        float coef = rsqrtf((float)max(deg_out[s], 1));
        int slot = row_start[d] + (int)cnt[(size_t)c * N_pad + d] + (int)lrank[e];
        epack[slot] = make_int2(s, __float_as_int(coef));
    }
}

// ---------------- fused SpMM + GEMM: one dst row per wave ----------------
// Each wave holds the full agg row across its 64 lanes (acc = column `lane`).
// y[r][c] = sum_k agg[r][k] * W[k][c] is done in-wave: a_k via v_readlane
// (SGPR, free FMA operand), W[k][lane] from a 16KB LDS copy (consecutive-lane
// addresses -> conflict-free broadcast-free reads). This replaces the separate
// gemm kernel (was 62.5us, latency-stalled on per-k s_load of W) and kills the
// agg round trip (25.6MB write + re-read).
__global__ __launch_bounds__(256, 6) void spmm_gemm_kernel(
        const float* __restrict__ x, const int* __restrict__ row_start,
        const int2* __restrict__ epack, const float* __restrict__ W,
        const float* __restrict__ bvec, float* __restrict__ y, int N) {
    __shared__ float Wl[DFEAT * DFEAT];
    int tid = threadIdx.x;
    {
        const float4* W4 = (const float4*)W;
        float4* Wl4 = (float4*)Wl;
        #pragma unroll
        for (int j = 0; j < 4; ++j) Wl4[tid + 256 * j] = W4[tid + 256 * j];
    }
    __syncthreads();

    int lane = tid & 63;
    int r = blockIdx.x * 4 + (tid >> 6);
    if (r >= N) return;
    int beg = row_start[r];
    int end = row_start[r + 1];
    float acc = 0.f;
    for (int cb = beg; cb < end; cb += 64) {
        int take = min(64, end - cb);
        int2 p = (lane < take) ? epack[cb + lane] : make_int2(0, 0);
        int j = 0;
        for (; j + 8 <= take; j += 8) {
            int sj[8]; float cj[8], v[8];
            #pragma unroll
            for (int u = 0; u < 8; ++u) {
                sj[u] = __shfl(p.x, j + u);
                cj[u] = __int_as_float(__shfl(p.y, j + u));
            }
            #pragma unroll
            for (int u = 0; u < 8; ++u) v[u] = x[(size_t)sj[u] * DFEAT + lane];
            #pragma unroll
            for (int u = 0; u < 8; ++u) acc = fmaf(v[u], cj[u], acc);
        }
        for (; j < take; ++j) {
            int s = __shfl(p.x, j);
            float c = __int_as_float(__shfl(p.y, j));
            acc = fmaf(x[(size_t)s * DFEAT + lane], c, acc);
        }
    }
    acc *= rsqrtf((float)max(end - beg, 1));   // norm_dst: acc = agg[r][lane]

    // ---- in-wave GEMM tail: y[r][lane] = b[lane] + sum_k agg[r][k]*W[k][lane]
    float y0 = 0.f, y1 = 0.f, y2 = 0.f, y3 = 0.f;
    int ai = __float_as_int(acc);
    #pragma unroll
    for (int k = 0; k < DFEAT; k += 4) {
        float a0 = __int_as_float(__builtin_amdgcn_readlane(ai, k));
        float a1 = __int_as_float(__builtin_amdgcn_readlane(ai, k + 1));
        float a2 = __int_as_float(__builtin_amdgcn_readlane(ai, k + 2));
        float a3 = __int_as_float(__builtin_amdgcn_readlane(ai, k + 3));
        y0 = fmaf(a0, Wl[(k    ) * DFEAT + lane], y0);
        y1 = fmaf(a1, Wl[(k + 1) * DFEAT + lane], y1);
        y2 = fmaf(a2, Wl[(k + 2) * DFEAT + lane], y2);
        y3 = fmaf(a3, Wl[(k + 3) * DFEAT + lane], y3);
    }
    y[(size_t)r * DFEAT + lane] = bvec[lane] + ((y0 + y1) + (y2 + y3));
}

// ---------------- BN stats: grid-stride column sums / sumsq over y ----------------
// stride is a multiple of 16 float4s, so each thread's float4-column group
// (tid & 15) is invariant -> pure register accumulation, one LDS reduce,
// 64 scalar atomics per block from 1024 blocks.
__global__ __launch_bounds__(256) void bnstat_kernel(
        const float* __restrict__ y, float* __restrict__ sums,
        float* __restrict__ sumsq, int n4) {
    float s[4] = {0.f, 0.f, 0.f, 0.f}, q[4] = {0.f, 0.f, 0.f, 0.f};
    int stride = gridDim.x * 256;
    for (int i = blockIdx.x * 256 + threadIdx.x; i < n4; i += stride) {
        float4 v = ((const float4*)y)[i];
        s[0] += v.x; q[0] = fmaf(v.x, v.x, q[0]);
        s[1] += v.y; q[1] = fmaf(v.y, v.y, q[1]);
        s[2] += v.z; q[2] = fmaf(v.z, v.z, q[2]);
        s[3] += v.w; q[3] = fmaf(v.w, v.w, q[3]);
    }
    __shared__ float ls[16][16][4];
    __shared__ float lq[16][16][4];
    int c4 = threadIdx.x & 15, slot = threadIdx.x >> 4;
    #pragma unroll
    for (int j = 0; j < 4; ++j) { ls[slot][c4][j] = s[j]; lq[slot][c4][j] = q[j]; }
    __syncthreads();
    for (int o = 8; o > 0; o >>= 1) {
        if (slot < o) {
            #pragma unroll
            for (int j = 0; j < 4; ++j) {
                ls[slot][c4][j] += ls[slot + o][c4][j];
                lq[slot][c4][j] += lq[slot + o][c4][j];
            }
        }
        __syncthreads();
    }
    if (slot == 0) {
        #pragma unroll
        for (int j = 0; j < 4; ++j) {
            atomicAdd(&sums[c4 * 4 + j],  ls[0][c4][j]);
            atomicAdd(&sumsq[c4 * 4 + j], lq[0][c4][j]);
        }
    }
}

// ---------------- BN (batch stats) + ReLU + residual, float4, in place on y ----------------
__global__ void bn_relu_res_kernel(const float* __restrict__ x,
                                   const float* __restrict__ sums,
                                   const float* __restrict__ sumsq,
                                   const float* __restrict__ gamma,
                                   const float* __restrict__ beta,
                                   float* __restrict__ y, int n4, float inv_n) {
    int i = blockIdx.x * blockDim.x + threadIdx.x;   // float4 index
    if (i < n4) {
        int c0 = (i << 2) & (DFEAT - 1);
        float4 yv = ((const float4*)y)[i];
        float4 xv = ((const float4*)x)[i];
        float o[4] = {yv.x, yv.y, yv.z, yv.w};
        float xi[4] = {xv.x, xv.y, xv.z, xv.w};
        #pragma unroll
        for (int k = 0; k < 4; ++k) {
            int c = c0 + k;
            float mean = sums[c] * inv_n;
            float var = sumsq[c] * inv_n - mean * mean;
            float inv = rsqrtf(var + EPSBN);
            float v = (o[k] - mean) * inv * gamma[c] + beta[c];
            o[k] = xi[k] + fmaxf(v, 0.f);
        }
        ((float4*)y)[i] = make_float4(o[0], o[1], o[2], o[3]);
    }
}

extern "C" void kernel_launch(void* const* d_in, const int* in_sizes, int n_in,
                              void* d_out, int out_size, void* d_ws, size_t ws_size,
                              hipStream_t stream) {
    const float* x     = (const float*)d_in[0];
    const int*   src   = (const int*)d_in[1];
    const int*   dst   = (const int*)d_in[2];
    const float* W     = (const float*)d_in[3];
    const float* bvec  = (const float*)d_in[4];
    const float* gamma = (const float*)d_in[5];
    const float* beta  = (const float*)d_in[6];
    float* out = (float*)d_out;   // y, written once by fused spmm+gemm

    const int n_nodes = in_sizes[0] / DFEAT;
    const int E = in_sizes[1];
    const int NB = (n_nodes + SCB - 1) / SCB;
    const int C = (E + CHUNK - 1) >> CHUNK_LG;          // edge chunks
    const int P = (n_nodes + RNG - 1) / RNG;            // node partitions
    const int N_pad = P * RNG;

    // ws: epack (E int2) | lrank (E u16) | cnt (C*N_pad u16) | deg_out N |
    //     sums 64 | sumsq 64 | deg_in N | row_start N+1 | bsum 64
    char* wsb = (char*)d_ws;
    int2* epack          = (int2*)wsb;
    unsigned short* lrank = (unsigned short*)(wsb + (size_t)E * 8);
    unsigned short* cnt   = lrank + E;
    int*  deg_out_i  = (int*)(cnt + (size_t)C * N_pad);
    float* sums      = (float*)(deg_out_i + n_nodes);
    float* sumsq     = sums + DFEAT;
    int*  deg_in_i   = (int*)(sumsq + DFEAT);
    int*  row_start  = deg_in_i + n_nodes;
    int*  bsum       = row_start + n_nodes + 1;

    // zero: deg_out + sums + sumsq (contiguous). deg_in/cnt fully overwritten.
    hipMemsetAsync(deg_out_i, 0, ((size_t)n_nodes + 2 * DFEAT) * sizeof(int), stream);

    hist2d_kernel<<<dim3(C, P), 256, 0, stream>>>(src, dst, lrank, cnt, deg_out_i,
                                                  E, n_nodes, N_pad);

    colscan_kernel<<<(n_nodes + 255) / 256, 256, 0, stream>>>(cnt, deg_in_i,
                                                              n_nodes, N_pad, C);

    scan1_kernel<<<NB, 256, 0, stream>>>(deg_in_i, bsum, n_nodes);
    scan2_kernel<<<1, 64, 0, stream>>>(bsum, row_start, NB, n_nodes);
    scan3_kernel<<<NB, 256, 0, stream>>>(deg_in_i, bsum, row_start, n_nodes);

    fill_kernel<<<(E + 255) / 256, 256, 0, stream>>>(src, dst, lrank, cnt, deg_out_i,
                                                     row_start, epack, E, N_pad);

    spmm_gemm_kernel<<<(n_nodes + 3) / 4, 256, 0, stream>>>(x, row_start, epack,
                                                            W, bvec, out, n_nodes);

    int n4 = n_nodes * DFEAT / 4;
    bnstat_kernel<<<1024, 256, 0, stream>>>(out, sums, sumsq, n4);

    bn_relu_res_kernel<<<(n4 + 255) / 256, 256, 0, stream>>>(
        x, sums, sumsq, gamma, beta, out, n4, 1.0f / (float)n_nodes);
}

// Round 2
// 292.086 us; speedup vs baseline: 1.2979x; 1.2979x over previous
//
#include <hip/hip_runtime.h>

#define DFEAT 64
#define EPSBN 1e-5f
#define SCB 2048      // elements per scan block (256 threads x 8)
#define CHUNK_LG 15
#define CHUNK (1 << CHUNK_LG)   // 32768 edges per chunk (637 blocks -> 2.5/CU)
#define RNG 8192      // nodes per partition (one packed 32KB LDS histogram)
#define BNG 512       // bnstat partial-reduction blocks (no atomics)

// ---------------- LDS-privatized PACKED dual histogram + chunk-local rank ----------------
// one 32KB LDS array: low16 = dst count, high16 = src count. int4 edge loads +
// manual prefetch.
__global__ __launch_bounds__(256) void hist2d_kernel(
        const int* __restrict__ src, const int* __restrict__ dst,
        unsigned short* __restrict__ lrank, unsigned short* __restrict__ cnt,
        int* __restrict__ deg_out, int E, int N, int N_pad) {
    __shared__ int h[RNG];
    int tid = threadIdx.x;
    int c = blockIdx.x, p = blockIdx.y;
    int nbeg = p * RNG;
    for (int i = tid; i < RNG; i += 256) h[i] = 0;
    __syncthreads();

    int ebeg = c << CHUNK_LG;
    int eend = min(ebeg + CHUNK, E);
    int nvec = (eend - ebeg) >> 2;              // full int4 groups
    const int4* src4 = (const int4*)(src + ebeg);
    const int4* dst4 = (const int4*)(dst + ebeg);

    int i = tid;
    int4 s4 = make_int4(0, 0, 0, 0), d4 = s4;
    if (i < nvec) { s4 = src4[i]; d4 = dst4[i]; }
    while (i < nvec) {
        int inext = i + 256;
        int4 sn = make_int4(0, 0, 0, 0), dn = sn;
        if (inext < nvec) { sn = src4[inext]; dn = dst4[inext]; }   // prefetch
        int e = ebeg + (i << 2);
        {
            unsigned int so, dof;
            so = (unsigned int)(s4.x - nbeg); if (so < RNG) atomicAdd(&h[so], 0x10000);
            so = (unsigned int)(s4.y - nbeg); if (so < RNG) atomicAdd(&h[so], 0x10000);
            so = (unsigned int)(s4.z - nbeg); if (so < RNG) atomicAdd(&h[so], 0x10000);
            so = (unsigned int)(s4.w - nbeg); if (so < RNG) atomicAdd(&h[so], 0x10000);
            dof = (unsigned int)(d4.x - nbeg);
            if (dof < RNG) lrank[e + 0] = (unsigned short)(atomicAdd(&h[dof], 1) & 0xffff);
            dof = (unsigned int)(d4.y - nbeg);
            if (dof < RNG) lrank[e + 1] = (unsigned short)(atomicAdd(&h[dof], 1) & 0xffff);
            dof = (unsigned int)(d4.z - nbeg);
            if (dof < RNG) lrank[e + 2] = (unsigned short)(atomicAdd(&h[dof], 1) & 0xffff);
            dof = (unsigned int)(d4.w - nbeg);
            if (dof < RNG) lrank[e + 3] = (unsigned short)(atomicAdd(&h[dof], 1) & 0xffff);
        }
        s4 = sn; d4 = dn; i = inext;
    }
    for (int e = ebeg + (nvec << 2) + tid; e < eend; e += 256) {
        unsigned int so = (unsigned int)(src[e] - nbeg);
        unsigned int dof = (unsigned int)(dst[e] - nbeg);
        if (so < RNG) atomicAdd(&h[so], 0x10000);
        if (dof < RNG) lrank[e] = (unsigned short)(atomicAdd(&h[dof], 1) & 0xffff);
    }
    __syncthreads();

    for (int i2 = tid; i2 < RNG; i2 += 256) {
        int n = nbeg + i2;
        if (n < N) {
            unsigned int v = (unsigned int)h[i2];
            unsigned int vo = v >> 16;
            if (vo) atomicAdd(&deg_out[n], (int)vo);   // contiguous lanes -> batched
            cnt[(size_t)c * N_pad + n] = (unsigned short)(v & 0xffffu);
        }
    }
}

// ---------------- column scan: per-node exclusive prefix over chunks ----------------
__global__ void colscan_kernel(unsigned short* __restrict__ cnt,
                               int* __restrict__ deg_in, int N, int N_pad, int C) {
    int n = blockIdx.x * blockDim.x + threadIdx.x;
    if (n >= N) return;
    int run = 0;
    for (int c = 0; c < C; ++c) {
        size_t idx = (size_t)c * N_pad + n;
        int v = cnt[idx];
        cnt[idx] = (unsigned short)run;
        run += v;
    }
    deg_in[n] = run;
}

// ---------------- scan pass 1: per-block sums of deg_in ----------------
__global__ void scan1_kernel(const int* __restrict__ deg, int* __restrict__ bsum, int N) {
    __shared__ int red[256];
    int t = threadIdx.x;
    int base = blockIdx.x * SCB + t * 8;
    int s = 0;
    #pragma unroll
    for (int j = 0; j < 8; ++j) { int idx = base + j; if (idx < N) s += deg[idx]; }
    red[t] = s;
    __syncthreads();
    for (int d = 128; d > 0; d >>= 1) { if (t < d) red[t] += red[t + d]; __syncthreads(); }
    if (t == 0) bsum[blockIdx.x] = red[0];
}

// ---------------- scan pass 2: one-wave shuffle exclusive scan (NB <= 64) ----------------
__global__ void scan2_kernel(int* __restrict__ bsum, int* __restrict__ row_start, int NB, int N) {
    int lane = threadIdx.x & 63;
    int v = (lane < NB) ? bsum[lane] : 0;
    int incl = v;
    #pragma unroll
    for (int off = 1; off < 64; off <<= 1) {
        int t = __shfl_up(incl, off);
        if (lane >= off) incl += t;
    }
    if (lane < NB) bsum[lane] = incl - v;
    if (lane == 63) row_start[N] = incl;   // total == E
}

// ---------------- scan pass 3: full exclusive scan -> row_start ----------------
__global__ void scan3_kernel(const int* __restrict__ deg, const int* __restrict__ bsum,
                             int* __restrict__ row_start, int N) {
    __shared__ int sc[256];
    int t = threadIdx.x;
    int base = blockIdx.x * SCB + t * 8;
    int v[8], ex[8];
    int s = 0;
    #pragma unroll
    for (int j = 0; j < 8; ++j) {
        int idx = base + j;
        v[j] = (idx < N) ? deg[idx] : 0;
        ex[j] = s;
        s += v[j];
    }
    sc[t] = s;
    __syncthreads();
    for (int d = 1; d < 256; d <<= 1) {
        int vv = (t >= d) ? sc[t - d] : 0;
        __syncthreads();
        sc[t] += vv;
        __syncthreads();
    }
    int toff = sc[t] - s + bsum[blockIdx.x];
    #pragma unroll
    for (int j = 0; j < 8; ++j) {
        int idx = base + j;
        if (idx < N) row_start[idx] = toff + ex[j];
    }
}

// ---------------- place edges: slot = row_start[d] + pref[c][d] + lrank[e] ----------------
__global__ void fill_kernel(const int* __restrict__ src, const int* __restrict__ dst,
                            const unsigned short* __restrict__ lrank,
                            const unsigned short* __restrict__ cnt,
                            const int* __restrict__ deg_out, const int* __restrict__ row_start,
                            int2* __restrict__ epack, int E, int N_pad) {
    int e = blockIdx.x * blockDim.x + threadIdx.x;
    if (e < E) {
        int d = dst[e], s = src[e];
        int c = e >> CHUNK_LG;
        float coef = rsqrtf((float)max(deg_out[s], 1));
        int slot = row_start[d] + (int)cnt[(size_t)c * N_pad + d] + (int)lrank[e];
        epack[slot] = make_int2(s, __float_as_int(coef));
    }
}

// ---------------- fused SpMM + GEMM: one dst row per wave ----------------
// Each wave holds the full agg row across its 64 lanes (acc = column `lane`).
// y[r][c] = sum_k agg[r][k] * W[k][c] is done in-wave: a_k via v_readlane
// (SGPR, free FMA operand), W[k][lane] from a 16KB LDS copy (consecutive-lane
// addresses -> conflict-free reads).
__global__ __launch_bounds__(256, 6) void spmm_gemm_kernel(
        const float* __restrict__ x, const int* __restrict__ row_start,
        const int2* __restrict__ epack, const float* __restrict__ W,
        const float* __restrict__ bvec, float* __restrict__ y, int N) {
    __shared__ float Wl[DFEAT * DFEAT];
    int tid = threadIdx.x;
    {
        const float4* W4 = (const float4*)W;
        float4* Wl4 = (float4*)Wl;
        #pragma unroll
        for (int j = 0; j < 4; ++j) Wl4[tid + 256 * j] = W4[tid + 256 * j];
    }
    __syncthreads();

    int lane = tid & 63;
    int r = blockIdx.x * 4 + (tid >> 6);
    if (r >= N) return;
    int beg = row_start[r];
    int end = row_start[r + 1];
    float acc = 0.f;
    for (int cb = beg; cb < end; cb += 64) {
        int take = min(64, end - cb);
        int2 p = (lane < take) ? epack[cb + lane] : make_int2(0, 0);
        int j = 0;
        for (; j + 8 <= take; j += 8) {
            int sj[8]; float cj[8], v[8];
            #pragma unroll
            for (int u = 0; u < 8; ++u) {
                sj[u] = __shfl(p.x, j + u);
                cj[u] = __int_as_float(__shfl(p.y, j + u));
            }
            #pragma unroll
            for (int u = 0; u < 8; ++u) v[u] = x[(size_t)sj[u] * DFEAT + lane];
            #pragma unroll
            for (int u = 0; u < 8; ++u) acc = fmaf(v[u], cj[u], acc);
        }
        for (; j < take; ++j) {
            int s = __shfl(p.x, j);
            float c = __int_as_float(__shfl(p.y, j));
            acc = fmaf(x[(size_t)s * DFEAT + lane], c, acc);
        }
    }
    acc *= rsqrtf((float)max(end - beg, 1));   // norm_dst: acc = agg[r][lane]

    // ---- in-wave GEMM tail: y[r][lane] = b[lane] + sum_k agg[r][k]*W[k][lane]
    float y0 = 0.f, y1 = 0.f, y2 = 0.f, y3 = 0.f;
    int ai = __float_as_int(acc);
    #pragma unroll
    for (int k = 0; k < DFEAT; k += 4) {
        float a0 = __int_as_float(__builtin_amdgcn_readlane(ai, k));
        float a1 = __int_as_float(__builtin_amdgcn_readlane(ai, k + 1));
        float a2 = __int_as_float(__builtin_amdgcn_readlane(ai, k + 2));
        float a3 = __int_as_float(__builtin_amdgcn_readlane(ai, k + 3));
        y0 = fmaf(a0, Wl[(k    ) * DFEAT + lane], y0);
        y1 = fmaf(a1, Wl[(k + 1) * DFEAT + lane], y1);
        y2 = fmaf(a2, Wl[(k + 2) * DFEAT + lane], y2);
        y3 = fmaf(a3, Wl[(k + 3) * DFEAT + lane], y3);
    }
    y[(size_t)r * DFEAT + lane] = bvec[lane] + ((y0 + y1) + (y2 + y3));
}

// ---------------- BN stats stage 1: per-block column partials, NO atomics ----------------
// stride is a multiple of 16 float4s, so each thread's float4-column group
// (tid & 15) is invariant -> pure register accumulation, one LDS tree reduce,
// then 128 coalesced partial stores per block. (Round-1 post-mortem: the
// previous single-kernel version funneled 1024 blocks x 128 same-address
// global atomicAdds -> 1024 serialized L2 RMWs per address ~= 85us of pure
// drain. Partials + tiny finalize kernel removes every atomic.)
__global__ __launch_bounds__(256) void bnstat1_kernel(
        const float* __restrict__ y, float* __restrict__ partial, int n4) {
    float s[4] = {0.f, 0.f, 0.f, 0.f}, q[4] = {0.f, 0.f, 0.f, 0.f};
    int stride = gridDim.x * 256;
    for (int i = blockIdx.x * 256 + threadIdx.x; i < n4; i += stride) {
        float4 v = ((const float4*)y)[i];
        s[0] += v.x; q[0] = fmaf(v.x, v.x, q[0]);
        s[1] += v.y; q[1] = fmaf(v.y, v.y, q[1]);
        s[2] += v.z; q[2] = fmaf(v.z, v.z, q[2]);
        s[3] += v.w; q[3] = fmaf(v.w, v.w, q[3]);
    }
    __shared__ float ls[16][16][4];
    __shared__ float lq[16][16][4];
    int c4 = threadIdx.x & 15, slot = threadIdx.x >> 4;
    #pragma unroll
    for (int j = 0; j < 4; ++j) { ls[slot][c4][j] = s[j]; lq[slot][c4][j] = q[j]; }
    __syncthreads();
    for (int o = 8; o > 0; o >>= 1) {
        if (slot < o) {
            #pragma unroll
            for (int j = 0; j < 4; ++j) {
                ls[slot][c4][j] += ls[slot + o][c4][j];
                lq[slot][c4][j] += lq[slot + o][c4][j];
            }
        }
        __syncthreads();
    }
    if (slot == 0) {
        float* p = partial + (size_t)blockIdx.x * 128;
        #pragma unroll
        for (int j = 0; j < 4; ++j) {
            p[c4 * 4 + j]      = ls[0][c4][j];   // cols 0..63: sums
            p[64 + c4 * 4 + j] = lq[0][c4][j];   // cols 64..127: sumsq
        }
    }
}

// ---------------- BN stats stage 2: finalize 512 partials -> sums/sumsq ----------------
// 256 threads: column j is summed by 2 threads (256 partials each, pipelined
// coalesced L2 loads), combined in LDS, stored directly (no zeroing needed).
__global__ void bnstat2_kernel(const float* __restrict__ partial,
                               float* __restrict__ sums, float* __restrict__ sumsq,
                               int G) {
    int t = threadIdx.x;
    int j = t & 127, h = t >> 7;      // h in {0,1}
    int half = G >> 1;
    float s = 0.f;
    const float* p = partial + (size_t)h * half * 128 + j;
    #pragma unroll 8
    for (int g = 0; g < half; ++g) s += p[(size_t)g * 128];
    __shared__ float red[2][128];
    red[h][j] = s;
    __syncthreads();
    if (h == 0) {
        float v = red[0][j] + red[1][j];
        if (j < 64) sums[j] = v;
        else        sumsq[j - 64] = v;
    }
}

// ---------------- BN (batch stats) + ReLU + residual, float4, in place on y ----------------
__global__ void bn_relu_res_kernel(const float* __restrict__ x,
                                   const float* __restrict__ sums,
                                   const float* __restrict__ sumsq,
                                   const float* __restrict__ gamma,
                                   const float* __restrict__ beta,
                                   float* __restrict__ y, int n4, float inv_n) {
    int i = blockIdx.x * blockDim.x + threadIdx.x;   // float4 index
    if (i < n4) {
        int c0 = (i << 2) & (DFEAT - 1);
        float4 yv = ((const float4*)y)[i];
        float4 xv = ((const float4*)x)[i];
        float o[4] = {yv.x, yv.y, yv.z, yv.w};
        float xi[4] = {xv.x, xv.y, xv.z, xv.w};
        #pragma unroll
        for (int k = 0; k < 4; ++k) {
            int c = c0 + k;
            float mean = sums[c] * inv_n;
            float var = sumsq[c] * inv_n - mean * mean;
            float inv = rsqrtf(var + EPSBN);
            float v = (o[k] - mean) * inv * gamma[c] + beta[c];
            o[k] = xi[k] + fmaxf(v, 0.f);
        }
        ((float4*)y)[i] = make_float4(o[0], o[1], o[2], o[3]);
    }
}

extern "C" void kernel_launch(void* const* d_in, const int* in_sizes, int n_in,
                              void* d_out, int out_size, void* d_ws, size_t ws_size,
                              hipStream_t stream) {
    const float* x     = (const float*)d_in[0];
    const int*   src   = (const int*)d_in[1];
    const int*   dst   = (const int*)d_in[2];
    const float* W     = (const float*)d_in[3];
    const float* bvec  = (const float*)d_in[4];
    const float* gamma = (const float*)d_in[5];
    const float* beta  = (const float*)d_in[6];
    float* out = (float*)d_out;   // y, written once by fused spmm+gemm

    const int n_nodes = in_sizes[0] / DFEAT;
    const int E = in_sizes[1];
    const int NB = (n_nodes + SCB - 1) / SCB;
    const int C = (E + CHUNK - 1) >> CHUNK_LG;          // edge chunks
    const int P = (n_nodes + RNG - 1) / RNG;            // node partitions
    const int N_pad = P * RNG;

    // ws: epack (E int2) | lrank (E u16) | cnt (C*N_pad u16) | deg_out N |
    //     sums 64 | sumsq 64 | deg_in N | row_start N+1 | bsum 64 | partial BNG*128
    char* wsb = (char*)d_ws;
    int2* epack          = (int2*)wsb;
    unsigned short* lrank = (unsigned short*)(wsb + (size_t)E * 8);
    unsigned short* cnt   = lrank + E;
    int*  deg_out_i  = (int*)(cnt + (size_t)C * N_pad);
    float* sums      = (float*)(deg_out_i + n_nodes);
    float* sumsq     = sums + DFEAT;
    int*  deg_in_i   = (int*)(sumsq + DFEAT);
    int*  row_start  = deg_in_i + n_nodes;
    int*  bsum       = row_start + n_nodes + 1;
    float* partial   = (float*)(bsum + 64);

    // zero: deg_out only (sums/sumsq now written directly by bnstat2).
    hipMemsetAsync(deg_out_i, 0, (size_t)n_nodes * sizeof(int), stream);

    hist2d_kernel<<<dim3(C, P), 256, 0, stream>>>(src, dst, lrank, cnt, deg_out_i,
                                                  E, n_nodes, N_pad);

    colscan_kernel<<<(n_nodes + 255) / 256, 256, 0, stream>>>(cnt, deg_in_i,
                                                              n_nodes, N_pad, C);

    scan1_kernel<<<NB, 256, 0, stream>>>(deg_in_i, bsum, n_nodes);
    scan2_kernel<<<1, 64, 0, stream>>>(bsum, row_start, NB, n_nodes);
    scan3_kernel<<<NB, 256, 0, stream>>>(deg_in_i, bsum, row_start, n_nodes);

    fill_kernel<<<(E + 255) / 256, 256, 0, stream>>>(src, dst, lrank, cnt, deg_out_i,
                                                     row_start, epack, E, N_pad);

    spmm_gemm_kernel<<<(n_nodes + 3) / 4, 256, 0, stream>>>(x, row_start, epack,
                                                            W, bvec, out, n_nodes);

    int n4 = n_nodes * DFEAT / 4;
    bnstat1_kernel<<<BNG, 256, 0, stream>>>(out, partial, n4);
    bnstat2_kernel<<<1, 256, 0, stream>>>(partial, sums, sumsq, BNG);

    bn_relu_res_kernel<<<(n4 + 255) / 256, 256, 0, stream>>>(
        x, sums, sumsq, gamma, beta, out, n4, 1.0f / (float)n_nodes);
}